// Round 6
// baseline (119.723 us; speedup 1.0000x reference)
//
#include <hip/hip_runtime.h>

// out = sum(h*h) - ||h^T F||_F^2,  h: [9600,128] f32, F: [9600,16] f32.
// M = h^T F is [128 x 16] = 2048 floats.
//
// ws floats: [0..2047] = M accumulators, [2048] = ssq, [2049] = done-counter.
//
// Single fused kernel: 240 blocks x 1024 threads (4 teams of 256).
// Each team: thread (k = tid&15, dg = tid>>4) accumulates M[dg*8+j, k] over
// its 10 rows. Teams combine via LDS; one atomicAdd per cell per block
// (depth 240). Last block to finish (device-scope counter) reads the 2048
// M cells with agent-scope atomic loads and writes the scalar.

#define NROWS        9600
#define BLOCKS       240
#define ROWS_PER_BLK (NROWS / BLOCKS)      // 40
#define ROWS_PER_TM  (ROWS_PER_BLK / 4)    // 10

__global__ __launch_bounds__(1024) void kmeans_fused(
    const float* __restrict__ h, const float* __restrict__ F,
    float* __restrict__ ws, float* __restrict__ out, int nrows) {

    const int t   = threadIdx.x;
    const int tm  = t >> 8;       // team 0..3
    const int tid = t & 255;
    const int k   = tid & 15;     // cluster col
    const int dg  = tid >> 4;     // d-group: d = dg*8 .. dg*8+7

    const int row0 = blockIdx.x * ROWS_PER_BLK + tm * ROWS_PER_TM;

    float acc[8] = {0.f,0.f,0.f,0.f,0.f,0.f,0.f,0.f};
    float ssq = 0.f;

    const float4* hb = reinterpret_cast<const float4*>(h);

    #pragma unroll 2
    for (int r = 0; r < ROWS_PER_TM; ++r) {
        const int n = row0 + r;
        if (n >= nrows) break;
        const float  f = F[n * 16 + k];
        const float4 a = hb[n * 32 + dg * 2 + 0];
        const float4 b = hb[n * 32 + dg * 2 + 1];
        acc[0] += a.x * f; acc[1] += a.y * f; acc[2] += a.z * f; acc[3] += a.w * f;
        acc[4] += b.x * f; acc[5] += b.y * f; acc[6] += b.z * f; acc[7] += b.w * f;
        if (k == 0) {
            ssq += a.x * a.x + a.y * a.y + a.z * a.z + a.w * a.w
                 + b.x * b.x + b.y * b.y + b.z * b.z + b.w * b.w;
        }
    }

    // ---- intra-block combine: teams 1..3 -> LDS, team 0 adds + atomics ----
    __shared__ float part[3][2048];
    __shared__ float ssq_part[64];

    if (tm > 0) {
        #pragma unroll
        for (int j = 0; j < 8; ++j)
            part[tm - 1][dg * 128 + j * 16 + k] = acc[j];
    }
    if (k == 0) ssq_part[t >> 4] = ssq;   // index = tm*16+dg, unique 0..63
    __syncthreads();

    if (tm == 0) {
        #pragma unroll
        for (int j = 0; j < 8; ++j) {
            const int c = dg * 128 + j * 16 + k;
            atomicAdd(&ws[c], acc[j] + part[0][c] + part[1][c] + part[2][c]);
        }
    }
    if (t < 64) {
        float s = ssq_part[t];
        #pragma unroll
        for (int off = 32; off; off >>= 1) s += __shfl_down(s, off);
        if (t == 0) atomicAdd(&ws[2048], s);
    }

    // ---- last-block-done: final reduction ----
    __shared__ bool is_last;
    __threadfence();      // drain this thread's atomics to the coherent point
    __syncthreads();
    if (t == 0) {
        unsigned prev = __hip_atomic_fetch_add(
            reinterpret_cast<unsigned*>(&ws[2049]), 1u,
            __ATOMIC_ACQ_REL, __HIP_MEMORY_SCOPE_AGENT);
        is_last = (prev == (unsigned)(gridDim.x - 1));
    }
    __syncthreads();
    if (!is_last) return;

    float s = 0.f;
    #pragma unroll
    for (int c = t; c < 2048; c += 1024) {
        const float m = __hip_atomic_load(&ws[c], __ATOMIC_RELAXED,
                                          __HIP_MEMORY_SCOPE_AGENT);
        s += m * m;
    }
    #pragma unroll
    for (int off = 32; off; off >>= 1) s += __shfl_down(s, off);
    __shared__ float red[16];
    if ((t & 63) == 0) red[t >> 6] = s;
    __syncthreads();
    if (t == 0) {
        float sm2 = 0.f;
        #pragma unroll
        for (int i = 0; i < 16; ++i) sm2 += red[i];
        const float ssq_tot = __hip_atomic_load(&ws[2048], __ATOMIC_RELAXED,
                                                __HIP_MEMORY_SCOPE_AGENT);
        out[0] = ssq_tot - sm2;   // hard write: d_out re-poisoned every replay
    }
}

extern "C" void kernel_launch(void* const* d_in, const int* in_sizes, int n_in,
                              void* d_out, int out_size, void* d_ws, size_t ws_size,
                              hipStream_t stream) {
    const float* h = (const float*)d_in[0];  // [N,128] f32
    const float* F = (const float*)d_in[1];  // [N,16]  f32
    float* out = (float*)d_out;
    float* ws  = (float*)d_ws;

    const int nrows = in_sizes[0] >> 7;      // 9600

    // Zero M accumulators + ssq + counter (ws is poisoned to 0xAA).
    hipMemsetAsync(ws, 0, 2056 * sizeof(float), stream);

    kmeans_fused<<<BLOCKS, 1024, 0, stream>>>(h, F, ws, out, nrows);
}

// Round 12
// 80.598 us; speedup vs baseline: 1.4854x; 1.4854x over previous
//
#include <hip/hip_runtime.h>

// out = sum(h*h) - ||h^T F||_F^2,  h: [9600,128] f32, F: [9600,16] f32.
// M = h^T F is [128 x 16] = 2048 floats.
//
// Round-6 post-mortem: 491,520 global atomicAdds onto 128 cache lines
// serialized at the coherent point (~3840 RMW/line ~= 68 us). This version
// has ZERO cross-block atomics: per-block partials via plain stores, then a
// tiny second kernel reduces them (kernel boundary provides coherence).
//
// ws layout (floats):
//   [0 .. 48*2048)            partial M, block b at [b*2048, b*2048+2048)
//   [98304 .. 98304+48)       partial ssq per block
// No memset needed: every slot K2 reads is written by K1 every call.

#define BLOCKS1  48
#define SSQ_OFF  (BLOCKS1 * 2048)   // 98304

__global__ __launch_bounds__(1024) void kmeans_part1(
    const float* __restrict__ h, const float* __restrict__ F,
    float* __restrict__ ws, int nrows) {

    const int t   = threadIdx.x;
    const int tm  = t >> 8;       // team 0..3
    const int tid = t & 255;
    const int k   = tid & 15;     // cluster col 0..15
    const int dg  = tid >> 4;     // d-group 0..15 (d = dg*8 .. dg*8+7)

    const int rpb   = (nrows + BLOCKS1 - 1) / BLOCKS1;   // 200
    const int rpt   = (rpb + 3) >> 2;                    // 50
    const int bbase = blockIdx.x * rpb;
    const int row0  = bbase + tm * rpt;
    int rowend = row0 + rpt;
    if (rowend > bbase + rpb) rowend = bbase + rpb;
    if (rowend > nrows)       rowend = nrows;

    float acc[8] = {0.f,0.f,0.f,0.f,0.f,0.f,0.f,0.f};
    float ssq = 0.f;

    const float4* hb = reinterpret_cast<const float4*>(h);

    #pragma unroll 5
    for (int n = row0; n < rowend; ++n) {
        const float  f = F[(n << 4) + k];
        const float4 a = hb[(n << 5) + (dg << 1) + 0];
        const float4 b = hb[(n << 5) + (dg << 1) + 1];
        acc[0] += a.x * f; acc[1] += a.y * f; acc[2] += a.z * f; acc[3] += a.w * f;
        acc[4] += b.x * f; acc[5] += b.y * f; acc[6] += b.z * f; acc[7] += b.w * f;
        if (k == 0) {
            ssq += a.x * a.x + a.y * a.y + a.z * a.z + a.w * a.w
                 + b.x * b.x + b.y * b.y + b.z * b.z + b.w * b.w;
        }
    }

    // ---- team combine in LDS ----
    // Store index swizzled by (j+dg)&7 so a wave's 64 lanes (4 dg x 16 k)
    // spread across all 32 banks at <=2-way aliasing (free). The mapping
    // (dg,j,k) -> slot is a bijection identical in every block, and K2 only
    // needs slot-wise consistency (we never materialize M itself).
    __shared__ float part[4][2048];
    __shared__ float ssqp[16];

    #pragma unroll
    for (int j = 0; j < 8; ++j)
        part[tm][(dg << 7) + (((j + dg) & 7) << 4) + k] = acc[j];

    // ssq: nonzero only on k==0 lanes; full-wave butterfly is still correct.
    #pragma unroll
    for (int off = 32; off; off >>= 1) ssq += __shfl_down(ssq, off);
    if ((t & 63) == 0) ssqp[t >> 6] = ssq;
    __syncthreads();

    // ---- write this block's partial (plain coalesced stores) ----
    const float2* p2 = reinterpret_cast<const float2*>(part);
    const float2 a2 = p2[         t];    // team 0, cells 2t,2t+1
    const float2 b2 = p2[1024  +  t];    // team 1
    const float2 c2 = p2[2048  +  t];    // team 2
    const float2 d2 = p2[3072  +  t];    // team 3
    float2 o;
    o.x = a2.x + b2.x + c2.x + d2.x;
    o.y = a2.y + b2.y + c2.y + d2.y;
    reinterpret_cast<float2*>(ws)[(blockIdx.x << 10) + t] = o;

    if (t == 0) {
        float sq = 0.f;
        #pragma unroll
        for (int i = 0; i < 16; ++i) sq += ssqp[i];
        ws[SSQ_OFF + blockIdx.x] = sq;
    }
}

__global__ __launch_bounds__(512) void kmeans_part2(
    const float* __restrict__ ws, float* __restrict__ out) {

    const int t = threadIdx.x;   // 512 threads, one float4 column each
    const float4* A = reinterpret_cast<const float4*>(ws);  // 512 float4/partial

    float4 m = make_float4(0.f, 0.f, 0.f, 0.f);
    #pragma unroll 8
    for (int b = 0; b < BLOCKS1; ++b) {
        const float4 v = A[(b << 9) + t];
        m.x += v.x; m.y += v.y; m.z += v.z; m.w += v.w;
    }
    float s = m.x * m.x + m.y * m.y + m.z * m.z + m.w * m.w;

    #pragma unroll
    for (int off = 32; off; off >>= 1) s += __shfl_down(s, off);
    __shared__ float red[8];
    if ((t & 63) == 0) red[t >> 6] = s;
    __syncthreads();

    if (t < 64) {
        // v = ssq partials (48 of them) minus the 8 per-wave ||M||^2 partials
        float v = (t < BLOCKS1) ? ws[SSQ_OFF + t] : 0.f;
        if (t < 8) v -= red[t];
        #pragma unroll
        for (int off = 32; off; off >>= 1) v += __shfl_down(v, off);
        if (t == 0) out[0] = v;   // hard write: d_out re-poisoned every replay
    }
}

extern "C" void kernel_launch(void* const* d_in, const int* in_sizes, int n_in,
                              void* d_out, int out_size, void* d_ws, size_t ws_size,
                              hipStream_t stream) {
    const float* h = (const float*)d_in[0];  // [N,128] f32
    const float* F = (const float*)d_in[1];  // [N,16]  f32
    float* out = (float*)d_out;
    float* ws  = (float*)d_ws;

    const int nrows = in_sizes[0] >> 7;      // 9600

    kmeans_part1<<<BLOCKS1, 1024, 0, stream>>>(h, F, ws, nrows);
    kmeans_part2<<<1, 512, 0, stream>>>(ws, out);
}